// Round 1
// baseline (37109.860 us; speedup 1.0000x reference)
//
#include <hip/hip_runtime.h>
#include <math.h>

#define D 128
#define D2 256
#define STK 48
#define SEQ 128
#define BATCH 32
#define RDPT 12
#define NSYN 64
#define NSEM 128
#define VOC 16384
#define EPSF 1e-6f
#define GB_C 0.8f
#define CG_C 2.0f

struct RParams {
  const int* input_ids;
  const int* prev_syn;
  const int* prev_sem;
  const float* emb_mag;
  const float* emb_phase;
  const float* cell_Wr;
  const float* cell_Wi;
  const float* norm_scale;
  const float* norm_shift;
  const float* modrelu_b;
  const float* vWr;
  const float* vWi;
  const float* oWr;
  const float* oWi;
  const float* halt_W;
  const float* halt_b;
  const float* stk_W;
  const float* stk_b;
  const float* cb_syn;
  const float* cb_sem;
  const float* ctxsyn_W;
  const float* ctxsyn_b;
  const float* ctxsem_W;
  const float* ctxsem_b;
  const float* adj_syn;
  const float* adj_sem;
  const float* gate_W;
  const float* gate_b;
  float* X;      // (B*S, 2D) rows of 0.5*(zq_syn + zq_sem)
  float* lossp;  // (B,) per-block raw sq-diff sums
};

__device__ __forceinline__ float waveRedSum(float v) {
  #pragma unroll
  for (int off = 32; off; off >>= 1) v += __shfl_down(v, off);
  return v;
}

// complex linear: out = (xr@Wr - xi@Wi, xi@Wr + xr@Wi), 512 threads,
// thread = (col 0..255, k-half 0..1). Inputs/outputs are LDS arrays.
__device__ __forceinline__ void clin512(const float* __restrict__ Wr,
                                        const float* __restrict__ Wi,
                                        const float* xr, const float* xi,
                                        float* outr, float* outi,
                                        float* part, int tid) {
  const int col = tid & 255;
  const int h = tid >> 8;
  const int j = col & 127;
  const int k0 = h * 64;
  float s = 0.f;
  if (col < 128) {
    #pragma unroll 8
    for (int k = k0; k < k0 + 64; ++k)
      s += xr[k] * Wr[k * D + j] - xi[k] * Wi[k * D + j];
  } else {
    #pragma unroll 8
    for (int k = k0; k < k0 + 64; ++k)
      s += xi[k] * Wr[k * D + j] + xr[k] * Wi[k * D + j];
  }
  part[tid] = s;
  __syncthreads();
  if (tid < 128)      outr[tid]       = part[tid] + part[tid + 256];
  else if (tid < 256) outi[tid - 128] = part[tid] + part[tid + 256];
  __syncthreads();
}

// one VQ: scores + argmin + zq gather + loss + (optionally) X-row write
template <int NCB, bool FIRST>
__device__ __forceinline__ void vq_step(const float* __restrict__ cb,
                                        const float* __restrict__ adj,
                                        const float* __restrict__ cW,
                                        const float* __restrict__ cbias,
                                        int slot, float* zfc, float* vqd,
                                        float* vqe, float* scal, int* icb,
                                        int tid, float& lossAcc, float* zqs,
                                        float* __restrict__ xout) {
  if (tid < NCB) {
    float dot = 0.f, nrm = 0.f;
    #pragma unroll 4
    for (int k = 0; k < D2; ++k) {
      float cv = cb[tid * D2 + k];
      dot += cv * zfc[k];
      nrm += cv * cv;
    }
    float e = cbias[tid];
    #pragma unroll 4
    for (int k = 0; k < D2; ++k) e += zfc[k] * cW[k * NCB + tid];
    vqd[tid] = nrm - 2.f * dot;
    vqe[tid] = e;
  }
  __syncthreads();
  if (tid < 64) {  // max of vqe
    float mv = vqe[tid];
    if (NCB == 128) mv = fmaxf(mv, vqe[tid + 64]);
    #pragma unroll
    for (int off = 32; off; off >>= 1) mv = fmaxf(mv, __shfl_down(mv, off));
    if (tid == 0) scal[12] = mv;
  }
  __syncthreads();
  if (tid < NCB) vqe[tid] = expf(vqe[tid] - scal[12]);
  __syncthreads();
  if (tid < 64) {  // sum of exp
    float sv = vqe[tid];
    if (NCB == 128) sv += vqe[tid + 64];
    sv = waveRedSum(sv);
    if (tid == 0) scal[12] = sv;
  }
  __syncthreads();
  if (tid < NCB) {
    int pidx = icb[slot];
    float adjv = adj[pidx * NCB + tid];
    float sig = 1.f / (1.f + expf(-adjv));
    vqd[tid] -= GB_C * sig + CG_C * (vqe[tid] / scal[12]);
  }
  __syncthreads();
  if (tid < 64) {  // argmin (first-min tiebreak)
    float dv = vqd[tid];
    int di = tid;
    if (NCB == 128) {
      float d2 = vqd[tid + 64];
      if (d2 < dv) { dv = d2; di = tid + 64; }
    }
    #pragma unroll
    for (int off = 32; off; off >>= 1) {
      float od = __shfl_down(dv, off);
      int oi = __shfl_down(di, off);
      if (od < dv || (od == dv && oi < di)) { dv = od; di = oi; }
    }
    if (tid == 0) icb[slot] = di;
  }
  __syncthreads();
  const int idx = icb[slot];
  if (tid < D2) {
    float zqv = cb[idx * D2 + tid];
    float df = zqv - zfc[tid];
    lossAcc += df * df;
    if (FIRST) zqs[tid] = zqv;
    else       xout[tid] = 0.5f * (zqs[tid] + zqv);
  }
  __syncthreads();
}

__global__ __launch_bounds__(512) void recur_kernel(RParams p) {
  __shared__ float mem[STK][D2];
  __shared__ float sptr[STK], nptr[STK], wmv[STK];
  __shared__ float zr[D], zi[D];
  __shared__ float rA[D], iA[D];
  __shared__ float cr[D], ci[D];
  __shared__ float vr[D], vi[D];
  __shared__ float zfc[D2];
  __shared__ float rd[D2];
  __shared__ float part[512];
  __shared__ float accr[D], acci[D], slr[D], sli[D];
  __shared__ float marr[D];
  __shared__ float scal[16];
  __shared__ int icb[2];
  __shared__ float vqd[NSEM], vqe[NSEM];
  __shared__ float zqs[D2];

  const int tid = threadIdx.x;
  const int b = blockIdx.x;

  for (int e = tid; e < STK * D2; e += 512) ((float*)mem)[e] = 0.f;
  if (tid < STK) sptr[tid] = (tid == 0) ? 1.f : 0.f;
  if (tid == 0) { icb[0] = p.prev_syn[b]; icb[1] = p.prev_sem[b]; }
  float lossAcc = 0.f;
  __syncthreads();

  for (int t = 0; t < SEQ; ++t) {
    const int id = p.input_ids[b * SEQ + t];
    if (tid < D) {
      float m = p.emb_mag[id * D + tid];
      float ph = p.emb_phase[id * D + tid];
      float sv, cv;
      sincosf(ph, &sv, &cv);
      zr[tid] = m * cv;
      zi[tid] = m * sv;
      accr[tid] = 0.f; acci[tid] = 0.f; slr[tid] = 0.f; sli[tid] = 0.f;
    }
    if (tid == 0) scal[0] = 1.f;  // rem
    __syncthreads();

    for (int n = 0; n < RDPT; ++n) {
      // ---- cell linear
      clin512(p.cell_Wr, p.cell_Wi, zr, zi, rA, iA, part, tid);
      // ---- magnitude norm + modReLU
      if (tid < D)
        marr[tid] = sqrtf(rA[tid] * rA[tid] + iA[tid] * iA[tid]) + EPSF;
      __syncthreads();
      {
        float rv = 0.f;
        if (tid < 64) rv = marr[tid] + marr[tid + 64];
        rv = waveRedSum(rv);
        if (tid == 0) scal[1] = rv * (1.f / D);
      }
      __syncthreads();
      const float mean = scal[1];
      {
        float rv = 0.f;
        if (tid < 64) {
          float d0 = marr[tid] - mean, d1 = marr[tid + 64] - mean;
          rv = d0 * d0 + d1 * d1;
        }
        rv = waveRedSum(rv);
        if (tid == 0) scal[2] = rsqrtf(rv * (1.f / (D - 1)) + EPSF);
      }
      __syncthreads();
      if (tid < D) {
        float m = marr[tid];
        float nm = (m - mean) * scal[2] * p.norm_scale[tid] + p.norm_shift[tid];
        float r_ = nm * rA[tid] / m;
        float i_ = nm * iA[tid] / m;
        float nn = sqrtf(r_ * r_ + i_ * i_) + EPSF;
        float s = fmaxf(nn + p.modrelu_b[tid], 0.f) / nn;
        cr[tid] = r_ * s;
        ci[tid] = i_ * s;
      }
      __syncthreads();
      clin512(p.vWr, p.vWi, cr, ci, vr, vi, part, tid);
      clin512(p.oWr, p.oWi, vr, vi, zfc, zfc + D, part, tid);
      // ---- halt + ctrl heads (one dot per wave, 4 waves)
      {
        int wv = tid >> 6, ln = tid & 63;
        if (wv < 4) {
          float s = 0.f;
          if (wv == 0) {
            for (int k = ln; k < D2; k += 64) s += zfc[k] * p.halt_W[k];
          } else {
            int c = wv - 1;
            for (int k = ln; k < D2; k += 64) s += zfc[k] * p.stk_W[k * 3 + c];
          }
          s = waveRedSum(s);
          if (ln == 0) scal[4 + wv] = s;
        }
      }
      __syncthreads();
      if (tid == 0) {
        float halt = 1.f / (1.f + expf(-(scal[4] + p.halt_b[0])));
        float e0 = scal[5] + p.stk_b[0];
        float e1 = scal[6] + p.stk_b[1];
        float e2 = scal[7] + p.stk_b[2];
        float mx = fmaxf(e0, fmaxf(e1, e2));
        float x0 = expf(e0 - mx), x1 = expf(e1 - mx), x2 = expf(e2 - mx);
        float sm = x0 + x1 + x2;
        scal[8] = x0 / sm; scal[9] = x1 / sm; scal[10] = x2 / sm;
        float rem = scal[0];
        scal[3] = (n == RDPT - 1) ? rem : rem * halt;  // w
        scal[0] = rem * (1.f - halt);
      }
      __syncthreads();
      // ---- differentiable stack
      const float push = scal[8], pop = scal[9], noop = scal[10];
      if (tid < STK) {
        float pj = sptr[tid];
        float pu = sptr[(tid + STK - 1) % STK];
        float pd = sptr[(tid + 1) % STK];
        nptr[tid] = push * pu + pop * pd + noop * pj;
        wmv[tid] = push * pu;
      }
      __syncthreads();
      if (tid < 64) {
        float v = (tid < STK) ? nptr[tid] : 0.f;
        v = waveRedSum(v);
        if (tid == 0) scal[11] = 1.f / (v + EPSF);
      }
      __syncthreads();
      if (tid < STK) nptr[tid] *= scal[11];
      __syncthreads();
      {
        int d = tid & 255, jh = tid >> 8;
        float zfd = zfc[d];
        float acc = 0.f;
        #pragma unroll 4
        for (int j2 = jh * 24; j2 < jh * 24 + 24; ++j2) {
          float wmj = wmv[j2];
          float m = mem[j2][d];
          m = wmj * zfd + m * (1.f - wmj);
          mem[j2][d] = m;
          acc += m * nptr[j2];
        }
        part[tid] = acc;
      }
      __syncthreads();
      if (tid < 256) rd[tid] = part[tid] + part[tid + 256];
      if (tid >= 256 && tid < 256 + STK) sptr[tid - 256] = nptr[tid - 256];
      __syncthreads();
      // ---- gate + gated residual + accumulators
      {
        int j = tid & 127, q = tid >> 7;
        const float* src = (q < 2) ? zfc : rd;
        const int kb = (q & 1) * D;
        float s = 0.f;
        #pragma unroll 8
        for (int kk = 0; kk < D; ++kk)
          s += src[kb + kk] * p.gate_W[(q * D + kk) * D + j];
        part[tid] = s;
      }
      __syncthreads();
      if (tid < D) {
        float g = part[tid] + part[tid + 128] + part[tid + 256] +
                  part[tid + 384] + p.gate_b[tid];
        g = 1.f / (1.f + expf(-g));
        float pr_ = zfc[tid], pi_ = zfc[D + tid];
        float rr_ = rd[tid], ri_ = rd[D + tid];
        float nzr = (1.f - g) * pr_ + g * pi_ + g * (rr_ - ri_);
        float nzi = (1.f - g) * pi_ - g * pr_ + g * (ri_ + rr_);
        zr[tid] = nzr;
        zi[tid] = nzi;
        float w = scal[3];
        accr[tid] += w * nzr;
        acci[tid] += w * nzi;
        slr[tid] += nzr * (1.f / RDPT);
        sli[tid] += nzi * (1.f / RDPT);
      }
      __syncthreads();
    }  // n

    // ---- VQ syn (zf = [accr|acci]) then sem (zf = [slr|sli])
    if (tid < D) { zfc[tid] = accr[tid]; zfc[D + tid] = acci[tid]; }
    __syncthreads();
    vq_step<NSYN, true>(p.cb_syn, p.adj_syn, p.ctxsyn_W, p.ctxsyn_b, 0, zfc,
                        vqd, vqe, scal, icb, tid, lossAcc, zqs, nullptr);
    if (tid < D) { zfc[tid] = slr[tid]; zfc[D + tid] = sli[tid]; }
    __syncthreads();
    vq_step<NSEM, false>(p.cb_sem, p.adj_sem, p.ctxsem_W, p.ctxsem_b, 1, zfc,
                         vqd, vqe, scal, icb, tid, lossAcc, zqs,
                         p.X + (size_t)(b * SEQ + t) * D2);
  }  // t

  // ---- block loss reduction
  part[tid] = lossAcc;
  __syncthreads();
  if (tid < 256) part[tid] += part[tid + 256];
  __syncthreads();
  if (tid < 128) part[tid] += part[tid + 128];
  __syncthreads();
  if (tid < 64) {
    float v = part[tid] + part[tid + 64];
    v = waveRedSum(v);
    if (tid == 0) p.lossp[b] = v;
  }
}

// logits = X @ dec_W + dec_b ; X (4096,256), dec_W (256,16384)
__global__ __launch_bounds__(256) void dec_kernel(const float* __restrict__ X,
                                                  const float* __restrict__ W,
                                                  const float* __restrict__ bias,
                                                  float* __restrict__ out) {
  __shared__ float A[32][D2];
  const int tid = threadIdx.x;
  const int bx = blockIdx.x;  // 0..127 col blocks (128 cols each)
  const int by = blockIdx.y;  // 0..127 row blocks (32 rows each)
  const float* xr = X + (size_t)by * 32 * D2;
  #pragma unroll
  for (int s = 0; s < 32; ++s) A[s][tid] = xr[s * D2 + tid];
  __syncthreads();
  const int ty = tid >> 5, tx = tid & 31;
  const int col0 = bx * 128 + tx * 4;
  const int r0 = ty * 4;
  float acc[4][4];
  #pragma unroll
  for (int r = 0; r < 4; ++r) {
    acc[r][0] = 0.f; acc[r][1] = 0.f; acc[r][2] = 0.f; acc[r][3] = 0.f;
  }
  const float* wp = W + col0;
  for (int k = 0; k < D2; k += 4) {
    float4 w0 = *(const float4*)(wp + (size_t)(k + 0) * VOC);
    float4 w1 = *(const float4*)(wp + (size_t)(k + 1) * VOC);
    float4 w2 = *(const float4*)(wp + (size_t)(k + 2) * VOC);
    float4 w3 = *(const float4*)(wp + (size_t)(k + 3) * VOC);
    #pragma unroll
    for (int r = 0; r < 4; ++r) {
      float4 a = *(const float4*)&A[r0 + r][k];
      acc[r][0] += a.x * w0.x + a.y * w1.x + a.z * w2.x + a.w * w3.x;
      acc[r][1] += a.x * w0.y + a.y * w1.y + a.z * w2.y + a.w * w3.y;
      acc[r][2] += a.x * w0.z + a.y * w1.z + a.z * w2.z + a.w * w3.z;
      acc[r][3] += a.x * w0.w + a.y * w1.w + a.z * w2.w + a.w * w3.w;
    }
  }
  float4 bv = *(const float4*)(bias + col0);
  #pragma unroll
  for (int r = 0; r < 4; ++r) {
    float4 o;
    o.x = acc[r][0] + bv.x; o.y = acc[r][1] + bv.y;
    o.z = acc[r][2] + bv.z; o.w = acc[r][3] + bv.w;
    *(float4*)(out + (size_t)(by * 32 + r0 + r) * VOC + col0) = o;
  }
}

__global__ void loss_kernel(const float* __restrict__ lp, float* __restrict__ out) {
  int l = threadIdx.x;
  float v = (l < BATCH) ? lp[l] : 0.f;
  v = waveRedSum(v);
  if (l == 0) out[0] = v * (1.25f / 8192.f);  // (1+CC)/(B*2D)
}

extern "C" void kernel_launch(void* const* d_in, const int* in_sizes, int n_in,
                              void* d_out, int out_size, void* d_ws,
                              size_t ws_size, hipStream_t stream) {
  RParams p;
  p.input_ids  = (const int*)d_in[0];
  p.prev_syn   = (const int*)d_in[1];
  p.prev_sem   = (const int*)d_in[2];
  p.emb_mag    = (const float*)d_in[3];
  p.emb_phase  = (const float*)d_in[4];
  p.cell_Wr    = (const float*)d_in[5];
  p.cell_Wi    = (const float*)d_in[6];
  p.norm_scale = (const float*)d_in[7];
  p.norm_shift = (const float*)d_in[8];
  p.modrelu_b  = (const float*)d_in[9];
  // d_in[10..13] = qW/kW: unused by the reference forward
  p.vWr        = (const float*)d_in[14];
  p.vWi        = (const float*)d_in[15];
  p.oWr        = (const float*)d_in[16];
  p.oWi        = (const float*)d_in[17];
  p.halt_W     = (const float*)d_in[18];
  p.halt_b     = (const float*)d_in[19];
  p.stk_W      = (const float*)d_in[20];
  p.stk_b      = (const float*)d_in[21];
  p.cb_syn     = (const float*)d_in[22];
  p.cb_sem     = (const float*)d_in[23];
  p.ctxsyn_W   = (const float*)d_in[24];
  p.ctxsyn_b   = (const float*)d_in[25];
  p.ctxsem_W   = (const float*)d_in[26];
  p.ctxsem_b   = (const float*)d_in[27];
  p.adj_syn    = (const float*)d_in[28];
  p.adj_sem    = (const float*)d_in[29];
  p.gate_W     = (const float*)d_in[30];
  p.gate_b     = (const float*)d_in[31];
  const float* dec_W = (const float*)d_in[32];
  const float* dec_b = (const float*)d_in[33];

  float* ws = (float*)d_ws;
  p.X = ws;                               // 4096*256 floats
  p.lossp = ws + (size_t)BATCH * SEQ * D2;  // 32 floats

  float* out = (float*)d_out;

  recur_kernel<<<BATCH, 512, 0, stream>>>(p);
  dec_kernel<<<dim3(VOC / 128, BATCH * SEQ / 32), 256, 0, stream>>>(p.X, dec_W,
                                                                    dec_b, out);
  loss_kernel<<<1, 64, 0, stream>>>(p.lossp, out + (size_t)BATCH * SEQ * VOC);
}

// Round 2
// 28416.357 us; speedup vs baseline: 1.3059x; 1.3059x over previous
//
#include <hip/hip_runtime.h>
#include <math.h>

#define D 128
#define D2 256
#define STK 48
#define SEQ 128
#define BATCH 32
#define RDPT 12
#define NSYN 64
#define NSEM 128
#define VOC 16384
#define EPSF 1e-6f
#define GB_C 0.8f
#define CG_C 2.0f

struct RParams {
  const int* input_ids;
  const int* prev_syn;
  const int* prev_sem;
  const float* emb_mag;
  const float* emb_phase;
  const float* cell_Wr;
  const float* cell_Wi;
  const float* norm_scale;
  const float* norm_shift;
  const float* modrelu_b;
  const float* VOr;   // precomputed v@o complex product (real)
  const float* VOi;   // (imag)
  const float* halt_W;
  const float* halt_b;
  const float* stk_W;
  const float* stk_b;
  const float* cb_syn;
  const float* cb_sem;
  const float* ctxsyn_W;
  const float* ctxsyn_b;
  const float* ctxsem_W;
  const float* ctxsem_b;
  const float* adj_syn;
  const float* adj_sem;
  const float* gate_W;
  const float* gate_b;
  float* X;      // (B*S, 2D) rows of 0.5*(zq_syn + zq_sem)
  float* lossp;  // (B,) per-block raw sq-diff sums
};

__device__ __forceinline__ float waveRedSum(float v) {
  #pragma unroll
  for (int off = 32; off; off >>= 1) v += __shfl_down(v, off);
  return v;
}

// one VQ: scores + argmin + zq gather + loss + (optionally) X-row write
template <int NCB, bool FIRST>
__device__ __forceinline__ void vq_step(const float* __restrict__ cb,
                                        const float* __restrict__ adj,
                                        const float* __restrict__ cW,
                                        const float* __restrict__ cbias,
                                        int slot, float* zfc, float* vqd,
                                        float* vqe, float* scal, int* icb,
                                        int tid, float& lossAcc, float* zqs,
                                        float* __restrict__ xout) {
  if (tid < NCB) {
    float dot = 0.f, nrm = 0.f;
    #pragma unroll 4
    for (int k = 0; k < D2; ++k) {
      float cv = cb[tid * D2 + k];
      dot += cv * zfc[k];
      nrm += cv * cv;
    }
    float e = cbias[tid];
    #pragma unroll 4
    for (int k = 0; k < D2; ++k) e += zfc[k] * cW[k * NCB + tid];
    vqd[tid] = nrm - 2.f * dot;
    vqe[tid] = e;
  }
  __syncthreads();
  if (tid < 64) {  // max of vqe
    float mv = vqe[tid];
    if (NCB == 128) mv = fmaxf(mv, vqe[tid + 64]);
    #pragma unroll
    for (int off = 32; off; off >>= 1) mv = fmaxf(mv, __shfl_down(mv, off));
    if (tid == 0) scal[12] = mv;
  }
  __syncthreads();
  if (tid < NCB) vqe[tid] = expf(vqe[tid] - scal[12]);
  __syncthreads();
  if (tid < 64) {  // sum of exp
    float sv = vqe[tid];
    if (NCB == 128) sv += vqe[tid + 64];
    sv = waveRedSum(sv);
    if (tid == 0) scal[12] = sv;
  }
  __syncthreads();
  if (tid < NCB) {
    int pidx = icb[slot];
    float adjv = adj[pidx * NCB + tid];
    float sig = 1.f / (1.f + expf(-adjv));
    vqd[tid] -= GB_C * sig + CG_C * (vqe[tid] / scal[12]);
  }
  __syncthreads();
  if (tid < 64) {  // argmin (first-min tiebreak)
    float dv = vqd[tid];
    int di = tid;
    if (NCB == 128) {
      float d2 = vqd[tid + 64];
      if (d2 < dv) { dv = d2; di = tid + 64; }
    }
    #pragma unroll
    for (int off = 32; off; off >>= 1) {
      float od = __shfl_down(dv, off);
      int oi = __shfl_down(di, off);
      if (od < dv || (od == dv && oi < di)) { dv = od; di = oi; }
    }
    if (tid == 0) icb[slot] = di;
  }
  __syncthreads();
  const int idx = icb[slot];
  if (tid < D2) {
    float zqv = cb[idx * D2 + tid];
    float df = zqv - zfc[tid];
    lossAcc += df * df;
    if (FIRST) zqs[tid] = zqv;
    else       xout[tid] = 0.5f * (zqs[tid] + zqv);
  }
  __syncthreads();
}

// complex-linear with register weights: thread = (col j in 0..127, kq in 0..3)
// writes per-thread partials to partr/parti; caller combines after barrier.
#define CLIN_REGS(WR, WI, XRP, XIP)                                       \
  {                                                                       \
    const float4* x4r = (const float4*)((XRP) + k0);                      \
    const float4* x4i = (const float4*)((XIP) + k0);                      \
    float a0 = 0.f, a1 = 0.f, a2 = 0.f, a3 = 0.f;                         \
    _Pragma("unroll")                                                     \
    for (int q = 0; q < 8; ++q) {                                         \
      float4 xa = x4r[q];                                                 \
      float4 xb = x4i[q];                                                 \
      a0 = fmaf(xa.x, WR[q*4+0], a0); a0 = fmaf(-xb.x, WI[q*4+0], a0);    \
      a1 = fmaf(xb.x, WR[q*4+0], a1); a1 = fmaf(xa.x, WI[q*4+0], a1);     \
      a2 = fmaf(xa.y, WR[q*4+1], a2); a2 = fmaf(-xb.y, WI[q*4+1], a2);    \
      a3 = fmaf(xb.y, WR[q*4+1], a3); a3 = fmaf(xa.y, WI[q*4+1], a3);     \
      a0 = fmaf(xa.z, WR[q*4+2], a0); a0 = fmaf(-xb.z, WI[q*4+2], a0);    \
      a1 = fmaf(xb.z, WR[q*4+2], a1); a1 = fmaf(xa.z, WI[q*4+2], a1);     \
      a2 = fmaf(xa.w, WR[q*4+3], a2); a2 = fmaf(-xb.w, WI[q*4+3], a2);    \
      a3 = fmaf(xb.w, WR[q*4+3], a3); a3 = fmaf(xa.w, WI[q*4+3], a3);     \
    }                                                                     \
    partr[tid] = a0 + a2;                                                 \
    parti[tid] = a1 + a3;                                                 \
  }                                                                       \
  __syncthreads();

__global__ __launch_bounds__(512) void recur_kernel(RParams p) {
  __shared__ float G1[D2 * D];  // gate_W rows 0..255, persistent (128KB)
  __shared__ float partr[512], parti[512], part[512];
  __shared__ float xr_[D], xi_[D];
  __shared__ float cr_[D], ci_[D];
  __shared__ float rA[D], iA[D], marr[D];
  __shared__ float zfc[D2], rd[D2];
  __shared__ float accr[D], acci[D], slr[D], sli[D];
  __shared__ float sptr[STK], nptrs[STK], wms[STK];
  __shared__ float shW[D2], sstW[D2 * 3];
  __shared__ float sns[D], nsh[D], smb[D], sgb[D];
  __shared__ float scal[16];
  __shared__ int icb[2];
  __shared__ float vqd[NSEM], vqe[NSEM], zqs[D2];

  const int tid = threadIdx.x;
  const int b = blockIdx.x;
  const int j = tid & 127;
  const int kq = tid >> 7;
  const int k0 = kq * 32;

  // ---- persistent weights -> registers (each element read exactly once)
  float cwr[32], cwi[32], owr[32], owi[32];
  #pragma unroll
  for (int kk = 0; kk < 32; ++kk) {
    cwr[kk] = p.cell_Wr[(k0 + kk) * D + j];
    cwi[kk] = p.cell_Wi[(k0 + kk) * D + j];
    owr[kk] = p.VOr[(k0 + kk) * D + j];
    owi[kk] = p.VOi[(k0 + kk) * D + j];
  }
  // ---- G1 (gate rows 0..255) -> LDS, once
  {
    const float4* g4 = (const float4*)p.gate_W;
    float4* l4 = (float4*)G1;
    for (int e = tid; e < D2 * D / 4; e += 512) l4[e] = g4[e];
  }
  if (tid < D2) shW[tid] = p.halt_W[tid];
  for (int e = tid; e < D2 * 3; e += 512) sstW[e] = p.stk_W[e];
  if (tid < D) {
    sns[tid] = p.norm_scale[tid];
    nsh[tid] = p.norm_shift[tid];
    smb[tid] = p.modrelu_b[tid];
    sgb[tid] = p.gate_b[tid];
  }
  if (tid < STK) sptr[tid] = (tid == 0) ? 1.f : 0.f;
  if (tid == 0) { icb[0] = p.prev_syn[b]; icb[1] = p.prev_sem[b]; }
  // ---- stack memory in registers: thread (d = tid&255, jh = tid>>8) owns rows jh*24..+23
  float memv[24];
  #pragma unroll
  for (int q = 0; q < 24; ++q) memv[q] = 0.f;
  const int md = tid & 255, mj = tid >> 8;
  float lossAcc = 0.f;
  __syncthreads();

  for (int t = 0; t < SEQ; ++t) {
    const int id = p.input_ids[b * SEQ + t];
    if (tid < D) {
      float m = p.emb_mag[id * D + tid];
      float ph = p.emb_phase[id * D + tid];
      float sv, cv;
      sincosf(ph, &sv, &cv);
      xr_[tid] = m * cv;
      xi_[tid] = m * sv;
      accr[tid] = 0.f; acci[tid] = 0.f; slr[tid] = 0.f; sli[tid] = 0.f;
    }
    if (tid == 0) scal[0] = 1.f;  // rem
    __syncthreads();

    for (int n = 0; n < RDPT; ++n) {
      // ---- cell complex linear (register weights)
      CLIN_REGS(cwr, cwi, xr_, xi_);
      if (tid < D) {
        float orr = partr[tid] + partr[tid + 128] + partr[tid + 256] + partr[tid + 384];
        float oii = parti[tid] + parti[tid + 128] + parti[tid + 256] + parti[tid + 384];
        rA[tid] = orr;
        iA[tid] = oii;
        marr[tid] = sqrtf(orr * orr + oii * oii) + EPSF;
      }
      __syncthreads();
      // ---- mean/var in one wave, one barrier
      if (tid < 64) {
        float m0 = marr[tid], m1 = marr[tid + 64];
        float s = m0 + m1;
        s = waveRedSum(s);
        s = __shfl(s, 0);
        float mean = s * (1.f / D);
        float d0 = m0 - mean, d1 = m1 - mean;
        float v = d0 * d0 + d1 * d1;
        v = waveRedSum(v);
        v = __shfl(v, 0);
        if (tid == 0) { scal[1] = mean; scal[2] = rsqrtf(v * (1.f / (D - 1)) + EPSF); }
      }
      __syncthreads();
      // ---- norm + modReLU
      if (tid < D) {
        float m = marr[tid];
        float nm = (m - scal[1]) * scal[2] * sns[tid] + nsh[tid];
        float r_ = nm * rA[tid] / m;
        float i_ = nm * iA[tid] / m;
        float nn = sqrtf(r_ * r_ + i_ * i_) + EPSF;
        float s = fmaxf(nn + smb[tid], 0.f) / nn;
        cr_[tid] = r_ * s;
        ci_[tid] = i_ * s;
      }
      __syncthreads();
      // ---- fused (v then o) complex linear (register weights)
      CLIN_REGS(owr, owi, cr_, ci_);
      if (tid < D) {
        zfc[tid]     = partr[tid] + partr[tid + 128] + partr[tid + 256] + partr[tid + 384];
        zfc[D + tid] = parti[tid] + parti[tid + 128] + parti[tid + 256] + parti[tid + 384];
      }
      __syncthreads();
      // ---- halt + ctrl heads
      {
        int wv = tid >> 6, ln = tid & 63;
        float s = 0.f;
        if (wv == 0) {
          for (int k = ln; k < D2; k += 64) s += zfc[k] * shW[k];
        } else if (wv < 4) {
          int c = wv - 1;
          for (int k = ln; k < D2; k += 64) s += zfc[k] * sstW[k * 3 + c];
        }
        s = waveRedSum(s);
        if (ln == 0 && wv < 4) scal[4 + wv] = s;
      }
      __syncthreads();
      if (tid == 0) {
        float halt = 1.f / (1.f + expf(-(scal[4] + p.halt_b[0])));
        float e0 = scal[5] + p.stk_b[0];
        float e1 = scal[6] + p.stk_b[1];
        float e2 = scal[7] + p.stk_b[2];
        float mx = fmaxf(e0, fmaxf(e1, e2));
        float x0 = expf(e0 - mx), x1 = expf(e1 - mx), x2 = expf(e2 - mx);
        float sm = x0 + x1 + x2;
        scal[8] = x0 / sm; scal[9] = x1 / sm; scal[10] = x2 / sm;
        float rem = scal[0];
        scal[3] = (n == RDPT - 1) ? rem : rem * halt;  // w
        scal[0] = rem * (1.f - halt);
      }
      __syncthreads();
      // ---- stack pointer pipeline in one wave
      if (tid < 64) {
        float push = scal[8], pop = scal[9], noop = scal[10];
        float pj = (tid < STK) ? sptr[tid] : 0.f;
        float pu = (tid < STK) ? sptr[(tid + STK - 1) % STK] : 0.f;
        float pd = (tid < STK) ? sptr[(tid + 1) % STK] : 0.f;
        float np_ = push * pu + pop * pd + noop * pj;
        float wm_ = push * pu;
        float s = (tid < STK) ? np_ : 0.f;
        s = waveRedSum(s);
        s = __shfl(s, 0);
        float inv = 1.f / (s + EPSF);
        if (tid < STK) {
          np_ *= inv;
          nptrs[tid] = np_;
          sptr[tid] = np_;
          wms[tid] = wm_;
        }
      }
      __syncthreads();
      // ---- stack memory update + read (mem in registers)
      {
        float zfd = zfc[md];
        float acc = 0.f;
        #pragma unroll
        for (int jj = 0; jj < 24; ++jj) {
          int jr = mj * 24 + jj;
          float wmj = wms[jr];
          memv[jj] = wmj * zfd + memv[jj] * (1.f - wmj);
          acc = fmaf(memv[jj], nptrs[jr], acc);
        }
        part[tid] = acc;
      }
      __syncthreads();
      if (tid < D2) rd[tid] = part[tid] + part[tid + 256];
      __syncthreads();
      // ---- gate: rows 0..255 from LDS (G1), rows 256..511 streamed from L2
      {
        float gacc = 0.f;
        if (kq < 2) {
          const int kb = kq * 128;
          #pragma unroll 16
          for (int kk = 0; kk < 128; ++kk)
            gacc = fmaf(zfc[kb + kk], G1[(kb + kk) * D + j], gacc);
        } else {
          const int kb = (kq - 2) * 128;
          const float* gp = p.gate_W + (size_t)(D2 + kb) * D + j;
          #pragma unroll 16
          for (int kk = 0; kk < 128; ++kk)
            gacc = fmaf(rd[kb + kk], gp[(size_t)kk * D], gacc);
        }
        part[tid] = gacc;
      }
      __syncthreads();
      // ---- gated residual + accumulators
      if (tid < D) {
        float g = part[tid] + part[tid + 128] + part[tid + 256] + part[tid + 384] + sgb[tid];
        g = 1.f / (1.f + expf(-g));
        float pr_ = zfc[tid], pi_ = zfc[D + tid];
        float rr_ = rd[tid], ri_ = rd[D + tid];
        float nzr = (1.f - g) * pr_ + g * pi_ + g * (rr_ - ri_);
        float nzi = (1.f - g) * pi_ - g * pr_ + g * (ri_ + rr_);
        xr_[tid] = nzr;
        xi_[tid] = nzi;
        float w = scal[3];
        accr[tid] += w * nzr;
        acci[tid] += w * nzi;
        slr[tid] += nzr * (1.f / RDPT);
        sli[tid] += nzi * (1.f / RDPT);
      }
      __syncthreads();
    }  // n

    // ---- VQ syn then sem
    if (tid < D) { zfc[tid] = accr[tid]; zfc[D + tid] = acci[tid]; }
    __syncthreads();
    vq_step<NSYN, true>(p.cb_syn, p.adj_syn, p.ctxsyn_W, p.ctxsyn_b, 0, zfc,
                        vqd, vqe, scal, icb, tid, lossAcc, zqs, nullptr);
    if (tid < D) { zfc[tid] = slr[tid]; zfc[D + tid] = sli[tid]; }
    __syncthreads();
    vq_step<NSEM, false>(p.cb_sem, p.adj_sem, p.ctxsem_W, p.ctxsem_b, 1, zfc,
                         vqd, vqe, scal, icb, tid, lossAcc, zqs,
                         p.X + (size_t)(b * SEQ + t) * D2);
  }  // t

  // ---- block loss reduction
  part[tid] = lossAcc;
  __syncthreads();
  if (tid < 256) part[tid] += part[tid + 256];
  __syncthreads();
  if (tid < 128) part[tid] += part[tid + 128];
  __syncthreads();
  if (tid < 64) {
    float v = part[tid] + part[tid + 64];
    v = waveRedSum(v);
    if (tid == 0) p.lossp[b] = v;
  }
}

// VO = V (complex) @ O (complex): VOr = vWr@oWr - vWi@oWi ; VOi = vWr@oOi + vWi@oWr
__global__ __launch_bounds__(256) void voprod_kernel(const float* __restrict__ vr,
                                                     const float* __restrict__ vi,
                                                     const float* __restrict__ orr,
                                                     const float* __restrict__ oii,
                                                     float* __restrict__ VOr,
                                                     float* __restrict__ VOi) {
  __shared__ float a_r[D], a_i[D];
  const int k = blockIdx.x;
  const int tid = threadIdx.x;
  if (tid < D) { a_r[tid] = vr[k * D + tid]; a_i[tid] = vi[k * D + tid]; }
  __syncthreads();
  const int m = tid & 127;
  const int half = tid >> 7;
  float acc = 0.f;
  if (half == 0) {
    #pragma unroll 8
    for (int jj = 0; jj < D; ++jj)
      acc += a_r[jj] * orr[jj * D + m] - a_i[jj] * oii[jj * D + m];
    VOr[k * D + m] = acc;
  } else {
    #pragma unroll 8
    for (int jj = 0; jj < D; ++jj)
      acc += a_r[jj] * oii[jj * D + m] + a_i[jj] * orr[jj * D + m];
    VOi[k * D + m] = acc;
  }
}

// logits = X @ dec_W + dec_b ; X (4096,256), dec_W (256,16384)
__global__ __launch_bounds__(256) void dec_kernel(const float* __restrict__ X,
                                                  const float* __restrict__ W,
                                                  const float* __restrict__ bias,
                                                  float* __restrict__ out) {
  __shared__ float A[32][D2];
  const int tid = threadIdx.x;
  const int bx = blockIdx.x;
  const int by = blockIdx.y;
  const float* xr = X + (size_t)by * 32 * D2;
  #pragma unroll
  for (int s = 0; s < 32; ++s) A[s][tid] = xr[s * D2 + tid];
  __syncthreads();
  const int ty = tid >> 5, tx = tid & 31;
  const int col0 = bx * 128 + tx * 4;
  const int r0 = ty * 4;
  float acc[4][4];
  #pragma unroll
  for (int r = 0; r < 4; ++r) {
    acc[r][0] = 0.f; acc[r][1] = 0.f; acc[r][2] = 0.f; acc[r][3] = 0.f;
  }
  const float* wp = W + col0;
  for (int k = 0; k < D2; k += 4) {
    float4 w0 = *(const float4*)(wp + (size_t)(k + 0) * VOC);
    float4 w1 = *(const float4*)(wp + (size_t)(k + 1) * VOC);
    float4 w2 = *(const float4*)(wp + (size_t)(k + 2) * VOC);
    float4 w3 = *(const float4*)(wp + (size_t)(k + 3) * VOC);
    #pragma unroll
    for (int r = 0; r < 4; ++r) {
      float4 a = *(const float4*)&A[r0 + r][k];
      acc[r][0] += a.x * w0.x + a.y * w1.x + a.z * w2.x + a.w * w3.x;
      acc[r][1] += a.x * w0.y + a.y * w1.y + a.z * w2.y + a.w * w3.y;
      acc[r][2] += a.x * w0.z + a.y * w1.z + a.z * w2.z + a.w * w3.z;
      acc[r][3] += a.x * w0.w + a.y * w1.w + a.z * w2.w + a.w * w3.w;
    }
  }
  float4 bv = *(const float4*)(bias + col0);
  #pragma unroll
  for (int r = 0; r < 4; ++r) {
    float4 o;
    o.x = acc[r][0] + bv.x; o.y = acc[r][1] + bv.y;
    o.z = acc[r][2] + bv.z; o.w = acc[r][3] + bv.w;
    *(float4*)(out + (size_t)(by * 32 + r0 + r) * VOC + col0) = o;
  }
}

__global__ void loss_kernel(const float* __restrict__ lp, float* __restrict__ out) {
  int l = threadIdx.x;
  float v = (l < BATCH) ? lp[l] : 0.f;
  v = waveRedSum(v);
  if (l == 0) out[0] = v * (1.25f / 8192.f);  // (1+CC)/(B*2D)
}

extern "C" void kernel_launch(void* const* d_in, const int* in_sizes, int n_in,
                              void* d_out, int out_size, void* d_ws,
                              size_t ws_size, hipStream_t stream) {
  float* ws = (float*)d_ws;
  float* X = ws;                                        // 4096*256
  float* lossp = ws + (size_t)BATCH * SEQ * D2;         // 32
  float* VOr = lossp + 64;                              // 16384
  float* VOi = VOr + D * D;                             // 16384

  RParams p;
  p.input_ids  = (const int*)d_in[0];
  p.prev_syn   = (const int*)d_in[1];
  p.prev_sem   = (const int*)d_in[2];
  p.emb_mag    = (const float*)d_in[3];
  p.emb_phase  = (const float*)d_in[4];
  p.cell_Wr    = (const float*)d_in[5];
  p.cell_Wi    = (const float*)d_in[6];
  p.norm_scale = (const float*)d_in[7];
  p.norm_shift = (const float*)d_in[8];
  p.modrelu_b  = (const float*)d_in[9];
  // d_in[10..13] = qW/kW: unused by the reference forward
  p.VOr        = VOr;
  p.VOi        = VOi;
  p.halt_W     = (const float*)d_in[18];
  p.halt_b     = (const float*)d_in[19];
  p.stk_W      = (const float*)d_in[20];
  p.stk_b      = (const float*)d_in[21];
  p.cb_syn     = (const float*)d_in[22];
  p.cb_sem     = (const float*)d_in[23];
  p.ctxsyn_W   = (const float*)d_in[24];
  p.ctxsyn_b   = (const float*)d_in[25];
  p.ctxsem_W   = (const float*)d_in[26];
  p.ctxsem_b   = (const float*)d_in[27];
  p.adj_syn    = (const float*)d_in[28];
  p.adj_sem    = (const float*)d_in[29];
  p.gate_W     = (const float*)d_in[30];
  p.gate_b     = (const float*)d_in[31];
  const float* dec_W = (const float*)d_in[32];
  const float* dec_b = (const float*)d_in[33];
  p.X = X;
  p.lossp = lossp;

  float* out = (float*)d_out;

  voprod_kernel<<<D, 256, 0, stream>>>((const float*)d_in[14], (const float*)d_in[15],
                                       (const float*)d_in[16], (const float*)d_in[17],
                                       VOr, VOi);
  recur_kernel<<<BATCH, 512, 0, stream>>>(p);
  dec_kernel<<<dim3(VOC / 128, BATCH * SEQ / 32), 256, 0, stream>>>(X, dec_W,
                                                                    dec_b, out);
  loss_kernel<<<1, 64, 0, stream>>>(lossp, out + (size_t)BATCH * SEQ * VOC);
}